// Round 8
// baseline (189.380 us; speedup 1.0000x reference)
//
#include <hip/hip_runtime.h>

#define INV_2PI 0.15915494309189535f

// One ATOMIC asm block per diff_round stage: 16 v_sin_f32 back-to-back.
// A single asm block cannot be torn apart or interleaved by the compiler
// (unlike per-instruction volatile asm, where non-volatile fmas were legally
// moved between the sins, re-serializing the chain — VGPR stayed 28 in
// R5-R7). Early-clobber outputs force 16 live results -> real trans-pipe ILP.
// v_sin_f32 takes REVOLUTIONS: computes sin(2*pi*x), no range reduction.
// s_nop 1 covers the trans->VALU read hazard (we bypass compiler hazard
// handling inside asm).
#define SIN16(c, s) asm volatile(                                  \
    "v_sin_f32 %0, %16\n\t"  "v_sin_f32 %1, %17\n\t"               \
    "v_sin_f32 %2, %18\n\t"  "v_sin_f32 %3, %19\n\t"               \
    "v_sin_f32 %4, %20\n\t"  "v_sin_f32 %5, %21\n\t"               \
    "v_sin_f32 %6, %22\n\t"  "v_sin_f32 %7, %23\n\t"               \
    "v_sin_f32 %8, %24\n\t"  "v_sin_f32 %9, %25\n\t"               \
    "v_sin_f32 %10, %26\n\t" "v_sin_f32 %11, %27\n\t"              \
    "v_sin_f32 %12, %28\n\t" "v_sin_f32 %13, %29\n\t"              \
    "v_sin_f32 %14, %30\n\t" "v_sin_f32 %15, %31\n\t"              \
    "s_nop 1"                                                      \
    : "=&v"(s[0]), "=&v"(s[1]), "=&v"(s[2]), "=&v"(s[3]),          \
      "=&v"(s[4]), "=&v"(s[5]), "=&v"(s[6]), "=&v"(s[7]),          \
      "=&v"(s[8]), "=&v"(s[9]), "=&v"(s[10]), "=&v"(s[11]),        \
      "=&v"(s[12]), "=&v"(s[13]), "=&v"(s[14]), "=&v"(s[15])       \
    : "v"(c[0]), "v"(c[1]), "v"(c[2]), "v"(c[3]),                  \
      "v"(c[4]), "v"(c[5]), "v"(c[6]), "v"(c[7]),                  \
      "v"(c[8]), "v"(c[9]), "v"(c[10]), "v"(c[11]),                \
      "v"(c[12]), "v"(c[13]), "v"(c[14]), "v"(c[15]))

#define SIN8(c, s) asm volatile(                                   \
    "v_sin_f32 %0, %8\n\t"  "v_sin_f32 %1, %9\n\t"                 \
    "v_sin_f32 %2, %10\n\t" "v_sin_f32 %3, %11\n\t"                \
    "v_sin_f32 %4, %12\n\t" "v_sin_f32 %5, %13\n\t"                \
    "v_sin_f32 %6, %14\n\t" "v_sin_f32 %7, %15\n\t"                \
    "s_nop 1"                                                      \
    : "=&v"(s[0]), "=&v"(s[1]), "=&v"(s[2]), "=&v"(s[3]),          \
      "=&v"(s[4]), "=&v"(s[5]), "=&v"(s[6]), "=&v"(s[7])           \
    : "v"(c[0]), "v"(c[1]), "v"(c[2]), "v"(c[3]),                  \
      "v"(c[4]), "v"(c[5]), "v"(c[6]), "v"(c[7]))

__device__ __forceinline__ void dround16(float* c) {
    float s[16];
    SIN16(c, s);
#pragma unroll
    for (int i = 0; i < 16; ++i) c[i] = __builtin_fmaf(-INV_2PI, s[i], c[i]);
}
__device__ __forceinline__ void dround8(float* c) {
    float s[8];
    SIN8(c, s);
#pragma unroll
    for (int i = 0; i < 8; ++i) c[i] = __builtin_fmaf(-INV_2PI, s[i], c[i]);
}

// Plain serial diff_round for the tiny wave-uniform id chain (overlaps with
// the 6 big mask stages; not on the throughput-critical path).
__device__ __forceinline__ float dround1(float x) {
    return __builtin_fmaf(-INV_2PI, __builtin_amdgcn_sinf(x), x);
}
__device__ __forceinline__ float hdr1(float x) { return dround1(dround1(dround1(x))); }

// One wave (64 lanes) per (area, mask-variant); each lane owns 4 contiguous
// pixels (16 mask channels) held live in c[16]; every diff_round stage is an
// atomic batch of 16 independent sins.
__global__ __launch_bounds__(256) void De_conv_areas_kernel(
    const float* __restrict__ img,       // [A,256,1] f32
    const float* __restrict__ mask,      // [A,256,4] f32
    const float* __restrict__ mask_alt,  // [A,256,4] f32
    const float* __restrict__ mask_id,   // [A,4]     f32
    float* __restrict__ out,             // [A,256]   f32  (output 0)
    float* __restrict__ out_alt,         // [A,256]   f32  (output 1)
    int n_areas)
{
    const int lane = threadIdx.x & 63;
    const int w    = blockIdx.x * (blockDim.x >> 6) + (threadIdx.x >> 6);
    const int area  = w >> 1;
    const int which = w & 1;                 // 0 -> mask/out, 1 -> mask_alt/out_alt
    if (area >= n_areas) return;

    const float* msk = which ? mask_alt : mask;   // wave-uniform select
    float*       dst = which ? out_alt  : out;

    const size_t pix = (size_t)area * 256 + (size_t)lane * 4;

    // Issue all VMEM up front; loads in flight while hb is computed.
    float4 idv = *(const float4*)(mask_id + (size_t)area * 4);
    const float4* mp = (const float4*)(msk + pix * 4);
    float4 p0 = mp[0], p1 = mp[1], p2 = mp[2], p3 = mp[3];
    float4 im = *(const float4*)(img + pix);

    // Per-area id (wave-uniform): harder_diff_round + eq-combine precompute:
    // t = ha*hb + (1-ha)*(1-hb) = ha*(2*hb-1) + (1-hb) = fma(ha, d, vb).
    float hb0 = hdr1(idv.x), hb1 = hdr1(idv.y), hb2 = hdr1(idv.z), hb3 = hdr1(idv.w);
    float d[4]  = { 2.f*hb0 - 1.f, 2.f*hb1 - 1.f, 2.f*hb2 - 1.f, 2.f*hb3 - 1.f };
    float vb[4] = { 1.f - hb0,     1.f - hb1,     1.f - hb2,     1.f - hb3 };

    float c[16] = { p0.x, p0.y, p0.z, p0.w,  p1.x, p1.y, p1.z, p1.w,
                    p2.x, p2.y, p2.z, p2.w,  p3.x, p3.y, p3.z, p3.w };

    // harder_diff_round(mask channels): 3 atomic batches of 16 sins.
    dround16(c); dround16(c); dround16(c);

    // differentiable_eq combine: one fma per channel.
#pragma unroll
    for (int i = 0; i < 16; ++i)
        c[i] = __builtin_fmaf(c[i], d[i & 3], vb[i & 3]);

    // harder_diff_round(eq): 3 atomic batches of 16.
    dround16(c); dround16(c); dround16(c);

    // differentiable_and tree: dround each channel (1 batch of 16),
    // pairwise products, dround the partials (batch of 8), final product.
    dround16(c);
    float p[8];
#pragma unroll
    for (int j = 0; j < 4; ++j) {
        p[2*j]   = c[4*j]   * c[4*j+1];
        p[2*j+1] = c[4*j+2] * c[4*j+3];
    }
    dround8(p);

    float imv[4] = { im.x, im.y, im.z, im.w };
    float m[4];
    float sm = 0.f, si = 0.f;
#pragma unroll
    for (int j = 0; j < 4; ++j) {
        m[j] = p[2*j] * p[2*j+1];
        sm += m[j]; si += m[j] * imv[j];
    }

    // Wave-wide butterfly reduction (64 lanes) for num/den.
#pragma unroll
    for (int off = 32; off; off >>= 1) {
        sm += __shfl_xor(sm, off, 64);
        si += __shfl_xor(si, off, 64);
    }

    // Guard 0/0: m >= 0 sums, so sm==0 implies every m==0 -> output 0.
    const float mean = (sm > 0.f) ? (si / sm) : 0.f;

    float4 o;
    o.x = m[0] * mean; o.y = m[1] * mean; o.z = m[2] * mean; o.w = m[3] * mean;
    *(float4*)(dst + pix) = o;                               // 16 B/lane, coalesced
}

extern "C" void kernel_launch(void* const* d_in, const int* in_sizes, int n_in,
                              void* d_out, int out_size, void* d_ws, size_t ws_size,
                              hipStream_t stream) {
    // setup_inputs() order (all float32 per reference):
    // 0: resized_image      [B,N,16,16,1]
    // 1: mask_combined      [B,N,16,16,4]
    // 2: mask_combined_alt  [B,N,16,16,4]
    // 3: initial_mask_id    [B,N,4]
    // 4: mask_new_bi_channel (unused)
    // 5: mask_index          (unused)
    const float* img      = (const float*)d_in[0];
    const float* mask     = (const float*)d_in[1];
    const float* mask_alt = (const float*)d_in[2];
    const float* mask_id  = (const float*)d_in[3];

    const int n_areas = out_size / 512;             // B*N = 16384
    float* out     = (float*)d_out;
    float* out_alt = out + (size_t)n_areas * 256;

    // 2 waves per area (one per mask variant), 4 waves per 256-thread block.
    const int n_waves = n_areas * 2;
    const int waves_per_block = 4;
    const int blocks = (n_waves + waves_per_block - 1) / waves_per_block;
    De_conv_areas_kernel<<<blocks, 256, 0, stream>>>(
        img, mask, mask_alt, mask_id, out, out_alt, n_areas);
}